// Round 12
// baseline (422.342 us; speedup 1.0000x reference)
//
#include <hip/hip_runtime.h>

#define N_NODES 50000
#define DIM 64
#define NPB 32                                  // nodes per bucket (dst >> 5)
#define NB 1563                                 // ceil(50000/32)
#define NCHUNK 128                              // edge chunks (= binning blocks)
#define ROWP 68                                 // padded LDS row (17-bank stride)

typedef unsigned short ushort_t;

__device__ __forceinline__ ushort_t f32_to_bf16(float f) {
    unsigned u = __float_as_uint(f);
    u += 0x7FFFu + ((u >> 16) & 1u);            // round-to-nearest-even
    return (ushort_t)(u >> 16);
}
__device__ __forceinline__ float bf16lo(unsigned u) { return __uint_as_float(u << 16); }
__device__ __forceinline__ float bf16hi(unsigned u) { return __uint_as_float(u & 0xFFFF0000u); }

// ---- K1: fused convert(x->bf16) + per-chunk bucket histogram + ticket reset ----
__global__ void convert_hist_kernel(const float* __restrict__ xf,
                                    ushort_t* __restrict__ xh,
                                    const int* __restrict__ col,
                                    int* __restrict__ localH,
                                    unsigned* __restrict__ done,
                                    int E, int chunk, int n4) {
    __shared__ int h[NB];
    int c = blockIdx.x;
    int tid = threadIdx.x;
    if (c == 0 && tid == 0) atomicExch(done, 0u);   // reset ticket for this replay
    for (int i = c * blockDim.x + tid; i < n4; i += gridDim.x * blockDim.x) {
        float4 v = *reinterpret_cast<const float4*>(xf + (size_t)i * 4);
        ushort4 hh;
        hh.x = f32_to_bf16(v.x);
        hh.y = f32_to_bf16(v.y);
        hh.z = f32_to_bf16(v.z);
        hh.w = f32_to_bf16(v.w);
        *reinterpret_cast<ushort4*>(xh + (size_t)i * 4) = hh;
    }
    for (int b = tid; b < NB; b += blockDim.x) h[b] = 0;
    __syncthreads();
    int beg = c * chunk, end = min(beg + chunk, E);
    int nfull = (end - beg) >> 2;
    for (int g = tid; g < nfull; g += blockDim.x) {
        int4 c4 = *reinterpret_cast<const int4*>(col + beg + g * 4);
        atomicAdd(&h[c4.x >> 5], 1);
        atomicAdd(&h[c4.y >> 5], 1);
        atomicAdd(&h[c4.z >> 5], 1);
        atomicAdd(&h[c4.w >> 5], 1);
    }
    for (int e = beg + nfull * 4 + tid; e < end; e += blockDim.x)
        atomicAdd(&h[col[e] >> 5], 1);
    __syncthreads();
    for (int b = tid; b < NB; b += blockDim.x)
        localH[(size_t)c * NB + b] = h[b];
}

// ---- K2: per-bucket prefix over chunks (in-place) + totals; LAST block scans
//      totals -> bucket_base (rocPRIM-style done-ticket, device atomics). ----
__global__ void chunk_offset_kernel(int* __restrict__ localH,
                                    int* __restrict__ bucket_total,
                                    int* __restrict__ bucket_base,
                                    unsigned* __restrict__ done) {
    int b = blockIdx.x;
    int lane = threadIdx.x;                     // single wave per bucket
    int running = 0;
    #pragma unroll
    for (int c0 = 0; c0 < NCHUNK; c0 += 64) {
        int c = c0 + lane;
        int v = localH[(size_t)c * NB + b];
        int incl = v;
        #pragma unroll
        for (int ofs = 1; ofs < 64; ofs <<= 1) {
            int t = __shfl_up(incl, ofs);
            if (lane >= ofs) incl += t;
        }
        localH[(size_t)c * NB + b] = running + incl - v;
        running += __shfl(incl, 63);
    }
    if (lane == 0) atomicExch(&bucket_total[b], running);
    __threadfence();                            // release totals before ticket
    unsigned t = 0;
    if (lane == 0) t = atomicAdd(done, 1u);
    t = __shfl((int)t, 0);
    if (t == NB - 1) {                          // last block: scan the totals
        __threadfence();                        // acquire
        int carry = 0;
        for (int b0 = 0; b0 < NB; b0 += 64) {
            int idx = b0 + lane;
            int v = (idx < NB) ? atomicAdd(&bucket_total[idx], 0) : 0;
            int incl = v;
            #pragma unroll
            for (int ofs = 1; ofs < 64; ofs <<= 1) {
                int u = __shfl_up(incl, ofs);
                if (lane >= ofs) incl += u;
            }
            if (idx < NB) bucket_base[idx] = carry + incl - v;
            carry += __shfl(incl, 63);
        }
        if (lane == 0) bucket_base[NB] = carry;
    }
}

// ---- K3: binning scatter — LDS atomics only; block-exclusive regions ----
__global__ void binning_kernel(const int* __restrict__ row,
                               const int* __restrict__ col,
                               const int* __restrict__ localH,
                               const int* __restrict__ bucket_base,
                               unsigned* __restrict__ packed,
                               int E, int chunk) {
    __shared__ int cursor[NB];
    int c = blockIdx.x;
    int tid = threadIdx.x;
    for (int b = tid; b < NB; b += blockDim.x)
        cursor[b] = localH[(size_t)c * NB + b] + bucket_base[b];
    __syncthreads();
    int beg = c * chunk, end = min(beg + chunk, E);
    int nfull = (end - beg) >> 2;
    for (int g = tid; g < nfull; g += blockDim.x) {
        int e = beg + g * 4;
        int4 d4 = *reinterpret_cast<const int4*>(col + e);
        int4 s4 = *reinterpret_cast<const int4*>(row + e);
        int p0 = atomicAdd(&cursor[d4.x >> 5], 1);
        packed[p0] = (unsigned)s4.x | ((unsigned)(d4.x & 31) << 16);
        int p1 = atomicAdd(&cursor[d4.y >> 5], 1);
        packed[p1] = (unsigned)s4.y | ((unsigned)(d4.y & 31) << 16);
        int p2 = atomicAdd(&cursor[d4.z >> 5], 1);
        packed[p2] = (unsigned)s4.z | ((unsigned)(d4.z & 31) << 16);
        int p3 = atomicAdd(&cursor[d4.w >> 5], 1);
        packed[p3] = (unsigned)s4.w | ((unsigned)(d4.w & 31) << 16);
    }
    for (int e = beg + nfull * 4 + tid; e < end; e += blockDim.x) {
        int d = col[e];
        int p = atomicAdd(&cursor[d >> 5], 1);
        packed[p] = (unsigned)row[e] | ((unsigned)(d & 31) << 16);
    }
}

// ---- K4: streaming aggregate — single pass, LDS float atomics, no sort ----
// 512 threads = 64 edge-groups x 8 lanes. Lane o covers dims o*8..o*8+7
// (one uint4 = 8 bf16). Accumulate into padded LDS tile acc[32][68].
template <bool BF16>
__global__ __launch_bounds__(512)
void aggregate_stream_kernel(const float* __restrict__ xf,
                             const ushort_t* __restrict__ xh,
                             const unsigned* __restrict__ packed,
                             const int* __restrict__ bucket_base,
                             float* __restrict__ out) {
    __shared__ float acc[NPB][ROWP];
    __shared__ int cnt[NPB];
    int b = blockIdx.x;
    int tid = threadIdx.x;                      // 0..511
    int gg = tid >> 3;                          // edge slot 0..63
    int o = tid & 7;                            // dim octet
    for (int i = tid; i < NPB * ROWP; i += 512) (&acc[0][0])[i] = 0.0f;
    if (tid < NPB) cnt[tid] = 0;
    __syncthreads();

    int seg_beg = bucket_base[b];
    int seg_end = bucket_base[b + 1];
    int i = seg_beg + gg;
    for (; i + 64 < seg_end; i += 128) {        // 2 edges per lane-group in flight
        unsigned v0 = packed[i];
        unsigned v1 = packed[i + 64];
        int ln0 = v0 >> 16, ln1 = v1 >> 16;
        if (BF16) {
            uint4 a0 = *reinterpret_cast<const uint4*>(xh + (size_t)(v0 & 0xFFFF) * DIM + o * 8);
            uint4 a1 = *reinterpret_cast<const uint4*>(xh + (size_t)(v1 & 0xFFFF) * DIM + o * 8);
            float* p0 = &acc[ln0][o * 8];
            atomicAdd(p0 + 0, bf16lo(a0.x)); atomicAdd(p0 + 1, bf16hi(a0.x));
            atomicAdd(p0 + 2, bf16lo(a0.y)); atomicAdd(p0 + 3, bf16hi(a0.y));
            atomicAdd(p0 + 4, bf16lo(a0.z)); atomicAdd(p0 + 5, bf16hi(a0.z));
            atomicAdd(p0 + 6, bf16lo(a0.w)); atomicAdd(p0 + 7, bf16hi(a0.w));
            float* p1 = &acc[ln1][o * 8];
            atomicAdd(p1 + 0, bf16lo(a1.x)); atomicAdd(p1 + 1, bf16hi(a1.x));
            atomicAdd(p1 + 2, bf16lo(a1.y)); atomicAdd(p1 + 3, bf16hi(a1.y));
            atomicAdd(p1 + 4, bf16lo(a1.z)); atomicAdd(p1 + 5, bf16hi(a1.z));
            atomicAdd(p1 + 6, bf16lo(a1.w)); atomicAdd(p1 + 7, bf16hi(a1.w));
        } else {
            const float* r0 = xf + (size_t)(v0 & 0xFFFF) * DIM + o * 8;
            const float* r1 = xf + (size_t)(v1 & 0xFFFF) * DIM + o * 8;
            float4 u0 = *reinterpret_cast<const float4*>(r0);
            float4 u1 = *reinterpret_cast<const float4*>(r0 + 4);
            float4 u2 = *reinterpret_cast<const float4*>(r1);
            float4 u3 = *reinterpret_cast<const float4*>(r1 + 4);
            float* p0 = &acc[ln0][o * 8];
            atomicAdd(p0 + 0, u0.x); atomicAdd(p0 + 1, u0.y);
            atomicAdd(p0 + 2, u0.z); atomicAdd(p0 + 3, u0.w);
            atomicAdd(p0 + 4, u1.x); atomicAdd(p0 + 5, u1.y);
            atomicAdd(p0 + 6, u1.z); atomicAdd(p0 + 7, u1.w);
            float* p1 = &acc[ln1][o * 8];
            atomicAdd(p1 + 0, u2.x); atomicAdd(p1 + 1, u2.y);
            atomicAdd(p1 + 2, u2.z); atomicAdd(p1 + 3, u2.w);
            atomicAdd(p1 + 4, u3.x); atomicAdd(p1 + 5, u3.y);
            atomicAdd(p1 + 6, u3.z); atomicAdd(p1 + 7, u3.w);
        }
        if (o == 0) {
            atomicAdd(&cnt[ln0], 1);
            atomicAdd(&cnt[ln1], 1);
        }
    }
    if (i < seg_end) {
        unsigned v0 = packed[i];
        int ln0 = v0 >> 16;
        if (BF16) {
            uint4 a0 = *reinterpret_cast<const uint4*>(xh + (size_t)(v0 & 0xFFFF) * DIM + o * 8);
            float* p0 = &acc[ln0][o * 8];
            atomicAdd(p0 + 0, bf16lo(a0.x)); atomicAdd(p0 + 1, bf16hi(a0.x));
            atomicAdd(p0 + 2, bf16lo(a0.y)); atomicAdd(p0 + 3, bf16hi(a0.y));
            atomicAdd(p0 + 4, bf16lo(a0.z)); atomicAdd(p0 + 5, bf16hi(a0.z));
            atomicAdd(p0 + 6, bf16lo(a0.w)); atomicAdd(p0 + 7, bf16hi(a0.w));
        } else {
            const float* r0 = xf + (size_t)(v0 & 0xFFFF) * DIM + o * 8;
            float4 u0 = *reinterpret_cast<const float4*>(r0);
            float4 u1 = *reinterpret_cast<const float4*>(r0 + 4);
            float* p0 = &acc[ln0][o * 8];
            atomicAdd(p0 + 0, u0.x); atomicAdd(p0 + 1, u0.y);
            atomicAdd(p0 + 2, u0.z); atomicAdd(p0 + 3, u0.w);
            atomicAdd(p0 + 4, u1.x); atomicAdd(p0 + 5, u1.y);
            atomicAdd(p0 + 6, u1.z); atomicAdd(p0 + 7, u1.w);
        }
        if (o == 0) atomicAdd(&cnt[ln0], 1);
    }
    __syncthreads();

    // writeout: thread t -> node t>>4, dim quad (t&15)*4; mean + float4 store
    int node = tid >> 4;
    int dq = (tid & 15) * 4;
    int gnode = b * NPB + node;
    if (gnode < N_NODES) {
        int c = cnt[node];
        float inv = (c > 0) ? 1.0f / (float)c : 0.0f;
        float4 vv = make_float4(acc[node][dq + 0] * inv, acc[node][dq + 1] * inv,
                                acc[node][dq + 2] * inv, acc[node][dq + 3] * inv);
        *reinterpret_cast<float4*>(out + (size_t)gnode * DIM + dq) = vv;
    }
}

extern "C" void kernel_launch(void* const* d_in, const int* in_sizes, int n_in,
                              void* d_out, int out_size, void* d_ws, size_t ws_size,
                              hipStream_t stream) {
    const float* x = (const float*)d_in[0];
    const int* edge_index = (const int*)d_in[1];  // [2, E] flat: row then col
    int E = in_sizes[1] / 2;
    const int* row = edge_index;
    const int* col = edge_index + E;
    float* out = (float*)d_out;

    int chunk = (((E + NCHUNK - 1) / NCHUNK) + 3) & ~3;   // multiple of 4
    int n4 = N_NODES * DIM / 4;

    // ws: bucket_total 1568 | bucket_base 1568 | done 16 | localH NCHUNK*NB | packed E | xh
    int* bucket_total = (int*)d_ws;
    int* bucket_base  = bucket_total + 1568;
    unsigned* done    = (unsigned*)(bucket_base + 1568);
    int* localH       = (int*)(done + 16);
    unsigned* packed  = (unsigned*)(localH + (size_t)NCHUNK * NB);
    ushort_t* xh      = (ushort_t*)(packed + E);
    size_t need_bf16  = (size_t)((char*)(xh + (size_t)N_NODES * DIM) - (char*)d_ws);
    bool use_bf16 = (ws_size >= need_bf16);

    convert_hist_kernel<<<NCHUNK, 1024, 0, stream>>>(x, xh, col, localH, done, E, chunk,
                                                     use_bf16 ? n4 : 0);
    chunk_offset_kernel<<<NB, 64, 0, stream>>>(localH, bucket_total, bucket_base, done);
    binning_kernel<<<NCHUNK, 1024, 0, stream>>>(row, col, localH, bucket_base,
                                                packed, E, chunk);
    if (use_bf16)
        aggregate_stream_kernel<true><<<NB, 512, 0, stream>>>(x, xh, packed, bucket_base, out);
    else
        aggregate_stream_kernel<false><<<NB, 512, 0, stream>>>(x, xh, packed, bucket_base, out);
}

// Round 13
// 160.057 us; speedup vs baseline: 2.6387x; 2.6387x over previous
//
#include <hip/hip_runtime.h>

#define N_NODES 50000
#define DIM 64
#define NPB 32                                  // nodes per bucket (dst >> 5)
#define NB 1563                                 // ceil(50000/32)
#define NCHUNK 128                              // edge chunks (= binning blocks)
#define CAP 1024                                // aggregate per-iteration LDS capacity

typedef unsigned short ushort_t;

__device__ __forceinline__ ushort_t f32_to_bf16(float f) {
    unsigned u = __float_as_uint(f);
    u += 0x7FFFu + ((u >> 16) & 1u);            // round-to-nearest-even
    return (ushort_t)(u >> 16);
}

__device__ __forceinline__ void acc_pair(float& a0, float& a1, unsigned u) {
    a0 += __uint_as_float(u << 16);             // low bf16  (even dim)
    a1 += __uint_as_float(u & 0xFFFF0000u);     // high bf16 (odd dim)
}

// ---- K1: fused convert(x->bf16) + per-chunk bucket histogram + ticket reset ----
__global__ void convert_hist_kernel(const float* __restrict__ xf,
                                    ushort_t* __restrict__ xh,
                                    const int* __restrict__ col,
                                    int* __restrict__ localH,
                                    unsigned* __restrict__ done,
                                    int E, int chunk, int n4) {
    __shared__ int h[NB];
    int c = blockIdx.x;
    int tid = threadIdx.x;
    if (c == 0 && tid == 0) atomicExch(done, 0u);   // reset ticket for this replay
    for (int i = c * blockDim.x + tid; i < n4; i += gridDim.x * blockDim.x) {
        float4 v = *reinterpret_cast<const float4*>(xf + (size_t)i * 4);
        ushort4 hh;
        hh.x = f32_to_bf16(v.x);
        hh.y = f32_to_bf16(v.y);
        hh.z = f32_to_bf16(v.z);
        hh.w = f32_to_bf16(v.w);
        *reinterpret_cast<ushort4*>(xh + (size_t)i * 4) = hh;
    }
    for (int b = tid; b < NB; b += blockDim.x) h[b] = 0;
    __syncthreads();
    int beg = c * chunk, end = min(beg + chunk, E);
    int nfull = (end - beg) >> 2;
    for (int g = tid; g < nfull; g += blockDim.x) {
        int4 c4 = *reinterpret_cast<const int4*>(col + beg + g * 4);
        atomicAdd(&h[c4.x >> 5], 1);
        atomicAdd(&h[c4.y >> 5], 1);
        atomicAdd(&h[c4.z >> 5], 1);
        atomicAdd(&h[c4.w >> 5], 1);
    }
    for (int e = beg + nfull * 4 + tid; e < end; e += blockDim.x)
        atomicAdd(&h[col[e] >> 5], 1);
    __syncthreads();
    for (int b = tid; b < NB; b += blockDim.x)
        localH[(size_t)c * NB + b] = h[b];
}

// ---- K2: per-bucket prefix over chunks (in-place) + totals; LAST block scans
//      totals -> bucket_base (rocPRIM-style done-ticket, device atomics). ----
__global__ void chunk_offset_kernel(int* __restrict__ localH,
                                    int* __restrict__ bucket_total,
                                    int* __restrict__ bucket_base,
                                    unsigned* __restrict__ done) {
    int b = blockIdx.x;
    int lane = threadIdx.x;                     // single wave per bucket
    int running = 0;
    #pragma unroll
    for (int c0 = 0; c0 < NCHUNK; c0 += 64) {
        int c = c0 + lane;
        int v = localH[(size_t)c * NB + b];
        int incl = v;
        #pragma unroll
        for (int ofs = 1; ofs < 64; ofs <<= 1) {
            int t = __shfl_up(incl, ofs);
            if (lane >= ofs) incl += t;
        }
        localH[(size_t)c * NB + b] = running + incl - v;
        running += __shfl(incl, 63);
    }
    if (lane == 0) atomicExch(&bucket_total[b], running);
    __threadfence();                            // release totals before ticket
    unsigned t = 0;
    if (lane == 0) t = atomicAdd(done, 1u);
    t = __shfl((int)t, 0);
    if (t == NB - 1) {                          // last block: scan the totals
        __threadfence();                        // acquire
        int carry = 0;
        for (int b0 = 0; b0 < NB; b0 += 64) {
            int idx = b0 + lane;
            int v = (idx < NB) ? atomicAdd(&bucket_total[idx], 0) : 0;
            int incl = v;
            #pragma unroll
            for (int ofs = 1; ofs < 64; ofs <<= 1) {
                int u = __shfl_up(incl, ofs);
                if (lane >= ofs) incl += u;
            }
            if (idx < NB) bucket_base[idx] = carry + incl - v;
            carry += __shfl(incl, 63);
        }
        if (lane == 0) bucket_base[NB] = carry;
    }
}

// ---- K3: binning scatter — LDS atomics only; block-exclusive regions ----
__global__ void binning_kernel(const int* __restrict__ row,
                               const int* __restrict__ col,
                               const int* __restrict__ localH,
                               const int* __restrict__ bucket_base,
                               unsigned* __restrict__ packed,
                               int E, int chunk) {
    __shared__ int cursor[NB];
    int c = blockIdx.x;
    int tid = threadIdx.x;
    for (int b = tid; b < NB; b += blockDim.x)
        cursor[b] = localH[(size_t)c * NB + b] + bucket_base[b];
    __syncthreads();
    int beg = c * chunk, end = min(beg + chunk, E);
    int nfull = (end - beg) >> 2;
    for (int g = tid; g < nfull; g += blockDim.x) {
        int e = beg + g * 4;
        int4 d4 = *reinterpret_cast<const int4*>(col + e);
        int4 s4 = *reinterpret_cast<const int4*>(row + e);
        int p0 = atomicAdd(&cursor[d4.x >> 5], 1);
        packed[p0] = (unsigned)s4.x | ((unsigned)(d4.x & 31) << 16);
        int p1 = atomicAdd(&cursor[d4.y >> 5], 1);
        packed[p1] = (unsigned)s4.y | ((unsigned)(d4.y & 31) << 16);
        int p2 = atomicAdd(&cursor[d4.z >> 5], 1);
        packed[p2] = (unsigned)s4.z | ((unsigned)(d4.z & 31) << 16);
        int p3 = atomicAdd(&cursor[d4.w >> 5], 1);
        packed[p3] = (unsigned)s4.w | ((unsigned)(d4.w & 31) << 16);
    }
    for (int e = beg + nfull * 4 + tid; e < end; e += blockDim.x) {
        int d = col[e];
        int p = atomicAdd(&cursor[d >> 5], 1);
        packed[p] = (unsigned)row[e] | ((unsigned)(d & 31) << 16);
    }
}

// ---- K4: per-bucket counting sort (LDS) + 8-lane/row gather + mean ----
// 512 threads = 8 waves; wave wv owns nodes [wv*4, wv*4+4).
// Lane split: g8 = lane>>3 (row slot 0..7), o = lane&7 (dim octet).
// One uint4 load = 8 bf16 dims of one row; 8 rows per instruction per wave.
template <bool BF16>
__global__ __launch_bounds__(512)
void aggregate_bucket_kernel(const float* __restrict__ xf,
                             const ushort_t* __restrict__ xh,
                             const unsigned* __restrict__ packed,
                             const int* __restrict__ bucket_base,
                             float* __restrict__ out) {
    __shared__ unsigned buf[CAP];
    __shared__ unsigned short srcs[CAP];
    __shared__ int hist[NPB];
    __shared__ int segoff[NPB];
    __shared__ int cursor[NPB];
    __shared__ int cnt_tot[NPB];

    int b = blockIdx.x;
    int tid = threadIdx.x;                      // 0..511
    int lane = tid & 63;
    int wv = tid >> 6;                          // wave 0..7
    int g8 = lane >> 3;                         // row slot 0..7
    int o = lane & 7;                           // dim octet (dims o*8 .. o*8+7)
    int seg_beg = bucket_base[b];
    int seg_end = bucket_base[b + 1];
    int node_base = b * NPB;
    int nnodes = min(NPB, N_NODES - node_base);

    float acc[4][8];
    #pragma unroll
    for (int r = 0; r < 4; ++r)
        #pragma unroll
        for (int k = 0; k < 8; ++k) acc[r][k] = 0.0f;
    if (tid < NPB) cnt_tot[tid] = 0;

    for (int cs = seg_beg; cs < seg_end; cs += CAP) {
        int m = min(CAP, seg_end - cs);
        __syncthreads();
        if (tid < NPB) hist[tid] = 0;
        __syncthreads();
        for (int i = tid; i < m; i += 512) {
            unsigned v = packed[cs + i];
            buf[i] = v;
            atomicAdd(&hist[v >> 16], 1);
        }
        __syncthreads();
        if (tid < NPB) {                        // lanes 0..31 of wave 0: scan 32 bins
            int v = hist[tid];
            int incl = v;
            #pragma unroll
            for (int ofs = 1; ofs < 32; ofs <<= 1) {
                int t = __shfl_up(incl, ofs);
                if (lane >= ofs) incl += t;
            }
            segoff[tid] = incl - v;
            cursor[tid] = incl - v;
            cnt_tot[tid] += v;
        }
        __syncthreads();
        for (int i = tid; i < m; i += 512) {
            unsigned v = buf[i];
            int p = atomicAdd(&cursor[v >> 16], 1);
            srcs[p] = (unsigned short)(v & 0xFFFF);
        }
        __syncthreads();
        #pragma unroll
        for (int r = 0; r < 4; ++r) {
            int ln = wv * 4 + r;
            int st = segoff[ln];
            int len = hist[ln];
            int j = 0;
            for (; j + 16 <= len; j += 16) {    // 16 rows in flight per wave
                int s0 = srcs[st + j + g8];
                int s1 = srcs[st + j + 8 + g8];
                if (BF16) {
                    uint4 a0 = *reinterpret_cast<const uint4*>(xh + (size_t)s0 * DIM + o * 8);
                    uint4 a1 = *reinterpret_cast<const uint4*>(xh + (size_t)s1 * DIM + o * 8);
                    acc_pair(acc[r][0], acc[r][1], a0.x);
                    acc_pair(acc[r][2], acc[r][3], a0.y);
                    acc_pair(acc[r][4], acc[r][5], a0.z);
                    acc_pair(acc[r][6], acc[r][7], a0.w);
                    acc_pair(acc[r][0], acc[r][1], a1.x);
                    acc_pair(acc[r][2], acc[r][3], a1.y);
                    acc_pair(acc[r][4], acc[r][5], a1.z);
                    acc_pair(acc[r][6], acc[r][7], a1.w);
                } else {
                    float4 u0 = *reinterpret_cast<const float4*>(xf + (size_t)s0 * DIM + o * 8);
                    float4 u1 = *reinterpret_cast<const float4*>(xf + (size_t)s0 * DIM + o * 8 + 4);
                    float4 u2 = *reinterpret_cast<const float4*>(xf + (size_t)s1 * DIM + o * 8);
                    float4 u3 = *reinterpret_cast<const float4*>(xf + (size_t)s1 * DIM + o * 8 + 4);
                    acc[r][0] += u0.x + u2.x; acc[r][1] += u0.y + u2.y;
                    acc[r][2] += u0.z + u2.z; acc[r][3] += u0.w + u2.w;
                    acc[r][4] += u1.x + u3.x; acc[r][5] += u1.y + u3.y;
                    acc[r][6] += u1.z + u3.z; acc[r][7] += u1.w + u3.w;
                }
            }
            for (; j < len; j += 8) {
                if (j + g8 < len) {
                    int s = srcs[st + j + g8];
                    if (BF16) {
                        uint4 a0 = *reinterpret_cast<const uint4*>(xh + (size_t)s * DIM + o * 8);
                        acc_pair(acc[r][0], acc[r][1], a0.x);
                        acc_pair(acc[r][2], acc[r][3], a0.y);
                        acc_pair(acc[r][4], acc[r][5], a0.z);
                        acc_pair(acc[r][6], acc[r][7], a0.w);
                    } else {
                        float4 u0 = *reinterpret_cast<const float4*>(xf + (size_t)s * DIM + o * 8);
                        float4 u1 = *reinterpret_cast<const float4*>(xf + (size_t)s * DIM + o * 8 + 4);
                        acc[r][0] += u0.x; acc[r][1] += u0.y;
                        acc[r][2] += u0.z; acc[r][3] += u0.w;
                        acc[r][4] += u1.x; acc[r][5] += u1.y;
                        acc[r][6] += u1.z; acc[r][7] += u1.w;
                    }
                }
            }
        }
    }
    __syncthreads();
    // reduce across row slots (xor 8,16,32) + mean + store
    #pragma unroll
    for (int r = 0; r < 4; ++r) {
        int ln = wv * 4 + r;
        #pragma unroll
        for (int k = 0; k < 8; ++k) {
            acc[r][k] += __shfl_xor(acc[r][k], 8);
            acc[r][k] += __shfl_xor(acc[r][k], 16);
            acc[r][k] += __shfl_xor(acc[r][k], 32);
        }
        if (g8 == 0 && ln < nnodes) {
            int c = cnt_tot[ln];
            float inv = (c > 0) ? 1.0f / (float)c : 0.0f;
            float4 lo = make_float4(acc[r][0] * inv, acc[r][1] * inv,
                                    acc[r][2] * inv, acc[r][3] * inv);
            float4 hi = make_float4(acc[r][4] * inv, acc[r][5] * inv,
                                    acc[r][6] * inv, acc[r][7] * inv);
            float* op = out + (size_t)(node_base + ln) * DIM + o * 8;
            *reinterpret_cast<float4*>(op) = lo;
            *reinterpret_cast<float4*>(op + 4) = hi;
        }
    }
}

extern "C" void kernel_launch(void* const* d_in, const int* in_sizes, int n_in,
                              void* d_out, int out_size, void* d_ws, size_t ws_size,
                              hipStream_t stream) {
    const float* x = (const float*)d_in[0];
    const int* edge_index = (const int*)d_in[1];  // [2, E] flat: row then col
    int E = in_sizes[1] / 2;
    const int* row = edge_index;
    const int* col = edge_index + E;
    float* out = (float*)d_out;

    int chunk = (((E + NCHUNK - 1) / NCHUNK) + 3) & ~3;   // multiple of 4
    int n4 = N_NODES * DIM / 4;

    // ws: bucket_total 1568 | bucket_base 1568 | done 16 | localH NCHUNK*NB | packed E | xh
    int* bucket_total = (int*)d_ws;
    int* bucket_base  = bucket_total + 1568;
    unsigned* done    = (unsigned*)(bucket_base + 1568);
    int* localH       = (int*)(done + 16);
    unsigned* packed  = (unsigned*)(localH + (size_t)NCHUNK * NB);
    ushort_t* xh      = (ushort_t*)(packed + E);
    size_t need_bf16  = (size_t)((char*)(xh + (size_t)N_NODES * DIM) - (char*)d_ws);
    bool use_bf16 = (ws_size >= need_bf16);

    convert_hist_kernel<<<NCHUNK, 1024, 0, stream>>>(x, xh, col, localH, done, E, chunk,
                                                     use_bf16 ? n4 : 0);
    chunk_offset_kernel<<<NB, 64, 0, stream>>>(localH, bucket_total, bucket_base, done);
    binning_kernel<<<NCHUNK, 1024, 0, stream>>>(row, col, localH, bucket_base,
                                                packed, E, chunk);
    if (use_bf16)
        aggregate_bucket_kernel<true><<<NB, 512, 0, stream>>>(x, xh, packed, bucket_base, out);
    else
        aggregate_bucket_kernel<false><<<NB, 512, 0, stream>>>(x, xh, packed, bucket_base, out);
}

// Round 14
// 69.474 us; speedup vs baseline: 6.0791x; 2.3038x over previous
//
#include <hip/hip_runtime.h>

#define N_NODES 50000
#define DIM 64
#define NPB 32                                  // nodes per bucket (dst >> 5)
#define NB 1563                                 // ceil(50000/32)
#define NCHUNK 128                              // edge chunks (= binning blocks)
#define CAP 1024                                // aggregate per-iteration LDS capacity

typedef unsigned short ushort_t;

__device__ __forceinline__ ushort_t f32_to_bf16(float f) {
    unsigned u = __float_as_uint(f);
    u += 0x7FFFu + ((u >> 16) & 1u);            // round-to-nearest-even
    return (ushort_t)(u >> 16);
}

__device__ __forceinline__ void acc_pair(float& a0, float& a1, unsigned u) {
    a0 += __uint_as_float(u << 16);             // low bf16  (even dim)
    a1 += __uint_as_float(u & 0xFFFF0000u);     // high bf16 (odd dim)
}

// ---- K1: fused convert(x->bf16) + per-chunk bucket histogram ----
__global__ void convert_hist_kernel(const float* __restrict__ xf,
                                    ushort_t* __restrict__ xh,
                                    const int* __restrict__ col,
                                    int* __restrict__ localH,
                                    int E, int chunk, int n4) {
    __shared__ int h[NB];
    int c = blockIdx.x;
    int tid = threadIdx.x;
    for (int i = c * blockDim.x + tid; i < n4; i += gridDim.x * blockDim.x) {
        float4 v = *reinterpret_cast<const float4*>(xf + (size_t)i * 4);
        ushort4 hh;
        hh.x = f32_to_bf16(v.x);
        hh.y = f32_to_bf16(v.y);
        hh.z = f32_to_bf16(v.z);
        hh.w = f32_to_bf16(v.w);
        *reinterpret_cast<ushort4*>(xh + (size_t)i * 4) = hh;
    }
    for (int b = tid; b < NB; b += blockDim.x) h[b] = 0;
    __syncthreads();
    int beg = c * chunk, end = min(beg + chunk, E);
    int nfull = (end - beg) >> 2;
    for (int g = tid; g < nfull; g += blockDim.x) {
        int4 c4 = *reinterpret_cast<const int4*>(col + beg + g * 4);
        atomicAdd(&h[c4.x >> 5], 1);
        atomicAdd(&h[c4.y >> 5], 1);
        atomicAdd(&h[c4.z >> 5], 1);
        atomicAdd(&h[c4.w >> 5], 1);
    }
    for (int e = beg + nfull * 4 + tid; e < end; e += blockDim.x)
        atomicAdd(&h[col[e] >> 5], 1);
    __syncthreads();
    for (int b = tid; b < NB; b += blockDim.x)
        localH[(size_t)c * NB + b] = h[b];
}

// ---- K2: thread-per-bucket serial scan over chunks (coalesced, in-place) ----
// Thread b: localH[c][b] <- exclusive running sum; bucket_total[b] <- total.
__global__ void chunk_offset_kernel(int* __restrict__ localH,
                                    int* __restrict__ bucket_total) {
    int b = blockIdx.x * blockDim.x + threadIdx.x;
    if (b >= NB) return;
    int running = 0;
    #pragma unroll 4
    for (int c = 0; c < NCHUNK; ++c) {
        int v = localH[(size_t)c * NB + b];     // coalesced across lanes
        localH[(size_t)c * NB + b] = running;
        running += v;
    }
    bucket_total[b] = running;
}

// ---- K3: scan of bucket totals (2 buckets/thread) -> bucket_base[0..NB] ----
__global__ void total_scan_kernel(const int* __restrict__ bucket_total,
                                  int* __restrict__ bucket_base) {
    __shared__ int sm[1024];
    int t = threadIdx.x;
    int b0 = 2 * t, b1 = 2 * t + 1;
    int v0 = (b0 < NB) ? bucket_total[b0] : 0;
    int v1 = (b1 < NB) ? bucket_total[b1] : 0;
    int s = v0 + v1;
    sm[t] = s;
    __syncthreads();
    for (int ofs = 1; ofs < 1024; ofs <<= 1) {
        int u = (t >= ofs) ? sm[t - ofs] : 0;
        __syncthreads();
        sm[t] += u;
        __syncthreads();
    }
    int excl = sm[t] - s;
    if (b0 < NB) bucket_base[b0] = excl;
    if (b1 < NB) bucket_base[b1] = excl + v0;
    if (t == 1023) bucket_base[NB] = sm[t];     // grand total
}

// ---- K4: binning scatter — LDS atomics only; block-exclusive regions ----
__global__ void binning_kernel(const int* __restrict__ row,
                               const int* __restrict__ col,
                               const int* __restrict__ localH,
                               const int* __restrict__ bucket_base,
                               unsigned* __restrict__ packed,
                               int E, int chunk) {
    __shared__ int cursor[NB];
    int c = blockIdx.x;
    int tid = threadIdx.x;
    for (int b = tid; b < NB; b += blockDim.x)
        cursor[b] = localH[(size_t)c * NB + b] + bucket_base[b];
    __syncthreads();
    int beg = c * chunk, end = min(beg + chunk, E);
    int nfull = (end - beg) >> 2;
    for (int g = tid; g < nfull; g += blockDim.x) {
        int e = beg + g * 4;
        int4 d4 = *reinterpret_cast<const int4*>(col + e);
        int4 s4 = *reinterpret_cast<const int4*>(row + e);
        int p0 = atomicAdd(&cursor[d4.x >> 5], 1);
        packed[p0] = (unsigned)s4.x | ((unsigned)(d4.x & 31) << 16);
        int p1 = atomicAdd(&cursor[d4.y >> 5], 1);
        packed[p1] = (unsigned)s4.y | ((unsigned)(d4.y & 31) << 16);
        int p2 = atomicAdd(&cursor[d4.z >> 5], 1);
        packed[p2] = (unsigned)s4.z | ((unsigned)(d4.z & 31) << 16);
        int p3 = atomicAdd(&cursor[d4.w >> 5], 1);
        packed[p3] = (unsigned)s4.w | ((unsigned)(d4.w & 31) << 16);
    }
    for (int e = beg + nfull * 4 + tid; e < end; e += blockDim.x) {
        int d = col[e];
        int p = atomicAdd(&cursor[d >> 5], 1);
        packed[p] = (unsigned)row[e] | ((unsigned)(d & 31) << 16);
    }
}

// ---- K5: per-bucket counting sort (LDS) + 8-lane/row gather + mean ----
// 512 threads = 8 waves; wave wv owns nodes [wv*4, wv*4+4).
// Lane split: g8 = lane>>3 (row slot 0..7), o = lane&7 (dim octet).
// One uint4 load = 8 bf16 dims of one row; 8 rows per instruction per wave.
template <bool BF16>
__global__ __launch_bounds__(512)
void aggregate_bucket_kernel(const float* __restrict__ xf,
                             const ushort_t* __restrict__ xh,
                             const unsigned* __restrict__ packed,
                             const int* __restrict__ bucket_base,
                             float* __restrict__ out) {
    __shared__ unsigned buf[CAP];
    __shared__ unsigned short srcs[CAP];
    __shared__ int hist[NPB];
    __shared__ int segoff[NPB];
    __shared__ int cursor[NPB];
    __shared__ int cnt_tot[NPB];

    int b = blockIdx.x;
    int tid = threadIdx.x;                      // 0..511
    int lane = tid & 63;
    int wv = tid >> 6;                          // wave 0..7
    int g8 = lane >> 3;                         // row slot 0..7
    int o = lane & 7;                           // dim octet (dims o*8 .. o*8+7)
    int seg_beg = bucket_base[b];
    int seg_end = bucket_base[b + 1];
    int node_base = b * NPB;
    int nnodes = min(NPB, N_NODES - node_base);

    float acc[4][8];
    #pragma unroll
    for (int r = 0; r < 4; ++r)
        #pragma unroll
        for (int k = 0; k < 8; ++k) acc[r][k] = 0.0f;
    if (tid < NPB) cnt_tot[tid] = 0;

    for (int cs = seg_beg; cs < seg_end; cs += CAP) {
        int m = min(CAP, seg_end - cs);
        __syncthreads();
        if (tid < NPB) hist[tid] = 0;
        __syncthreads();
        for (int i = tid; i < m; i += 512) {
            unsigned v = packed[cs + i];
            buf[i] = v;
            atomicAdd(&hist[v >> 16], 1);
        }
        __syncthreads();
        if (tid < NPB) {                        // lanes 0..31 of wave 0: scan 32 bins
            int v = hist[tid];
            int incl = v;
            #pragma unroll
            for (int ofs = 1; ofs < 32; ofs <<= 1) {
                int t = __shfl_up(incl, ofs);
                if (lane >= ofs) incl += t;
            }
            segoff[tid] = incl - v;
            cursor[tid] = incl - v;
            cnt_tot[tid] += v;
        }
        __syncthreads();
        for (int i = tid; i < m; i += 512) {
            unsigned v = buf[i];
            int p = atomicAdd(&cursor[v >> 16], 1);
            srcs[p] = (unsigned short)(v & 0xFFFF);
        }
        __syncthreads();
        #pragma unroll
        for (int r = 0; r < 4; ++r) {
            int ln = wv * 4 + r;
            int st = segoff[ln];
            int len = hist[ln];
            int j = 0;
            for (; j + 16 <= len; j += 16) {    // 16 rows in flight per wave
                int s0 = srcs[st + j + g8];
                int s1 = srcs[st + j + 8 + g8];
                if (BF16) {
                    uint4 a0 = *reinterpret_cast<const uint4*>(xh + (size_t)s0 * DIM + o * 8);
                    uint4 a1 = *reinterpret_cast<const uint4*>(xh + (size_t)s1 * DIM + o * 8);
                    acc_pair(acc[r][0], acc[r][1], a0.x);
                    acc_pair(acc[r][2], acc[r][3], a0.y);
                    acc_pair(acc[r][4], acc[r][5], a0.z);
                    acc_pair(acc[r][6], acc[r][7], a0.w);
                    acc_pair(acc[r][0], acc[r][1], a1.x);
                    acc_pair(acc[r][2], acc[r][3], a1.y);
                    acc_pair(acc[r][4], acc[r][5], a1.z);
                    acc_pair(acc[r][6], acc[r][7], a1.w);
                } else {
                    float4 u0 = *reinterpret_cast<const float4*>(xf + (size_t)s0 * DIM + o * 8);
                    float4 u1 = *reinterpret_cast<const float4*>(xf + (size_t)s0 * DIM + o * 8 + 4);
                    float4 u2 = *reinterpret_cast<const float4*>(xf + (size_t)s1 * DIM + o * 8);
                    float4 u3 = *reinterpret_cast<const float4*>(xf + (size_t)s1 * DIM + o * 8 + 4);
                    acc[r][0] += u0.x + u2.x; acc[r][1] += u0.y + u2.y;
                    acc[r][2] += u0.z + u2.z; acc[r][3] += u0.w + u2.w;
                    acc[r][4] += u1.x + u3.x; acc[r][5] += u1.y + u3.y;
                    acc[r][6] += u1.z + u3.z; acc[r][7] += u1.w + u3.w;
                }
            }
            for (; j < len; j += 8) {
                if (j + g8 < len) {
                    int s = srcs[st + j + g8];
                    if (BF16) {
                        uint4 a0 = *reinterpret_cast<const uint4*>(xh + (size_t)s * DIM + o * 8);
                        acc_pair(acc[r][0], acc[r][1], a0.x);
                        acc_pair(acc[r][2], acc[r][3], a0.y);
                        acc_pair(acc[r][4], acc[r][5], a0.z);
                        acc_pair(acc[r][6], acc[r][7], a0.w);
                    } else {
                        float4 u0 = *reinterpret_cast<const float4*>(xf + (size_t)s * DIM + o * 8);
                        float4 u1 = *reinterpret_cast<const float4*>(xf + (size_t)s * DIM + o * 8 + 4);
                        acc[r][0] += u0.x; acc[r][1] += u0.y;
                        acc[r][2] += u0.z; acc[r][3] += u0.w;
                        acc[r][4] += u1.x; acc[r][5] += u1.y;
                        acc[r][6] += u1.z; acc[r][7] += u1.w;
                    }
                }
            }
        }
    }
    __syncthreads();
    // reduce across row slots (xor 8,16,32) + mean + store
    #pragma unroll
    for (int r = 0; r < 4; ++r) {
        int ln = wv * 4 + r;
        #pragma unroll
        for (int k = 0; k < 8; ++k) {
            acc[r][k] += __shfl_xor(acc[r][k], 8);
            acc[r][k] += __shfl_xor(acc[r][k], 16);
            acc[r][k] += __shfl_xor(acc[r][k], 32);
        }
        if (g8 == 0 && ln < nnodes) {
            int c = cnt_tot[ln];
            float inv = (c > 0) ? 1.0f / (float)c : 0.0f;
            float4 lo = make_float4(acc[r][0] * inv, acc[r][1] * inv,
                                    acc[r][2] * inv, acc[r][3] * inv);
            float4 hi = make_float4(acc[r][4] * inv, acc[r][5] * inv,
                                    acc[r][6] * inv, acc[r][7] * inv);
            float* op = out + (size_t)(node_base + ln) * DIM + o * 8;
            *reinterpret_cast<float4*>(op) = lo;
            *reinterpret_cast<float4*>(op + 4) = hi;
        }
    }
}

extern "C" void kernel_launch(void* const* d_in, const int* in_sizes, int n_in,
                              void* d_out, int out_size, void* d_ws, size_t ws_size,
                              hipStream_t stream) {
    const float* x = (const float*)d_in[0];
    const int* edge_index = (const int*)d_in[1];  // [2, E] flat: row then col
    int E = in_sizes[1] / 2;
    const int* row = edge_index;
    const int* col = edge_index + E;
    float* out = (float*)d_out;

    int chunk = (((E + NCHUNK - 1) / NCHUNK) + 3) & ~3;   // multiple of 4
    int n4 = N_NODES * DIM / 4;

    // ws: bucket_total 1568 | bucket_base 1568 | localH NCHUNK*NB | packed E | xh
    int* bucket_total = (int*)d_ws;
    int* bucket_base  = bucket_total + 1568;
    int* localH       = bucket_base + 1568;
    unsigned* packed  = (unsigned*)(localH + (size_t)NCHUNK * NB);
    ushort_t* xh      = (ushort_t*)(packed + E);
    size_t need_bf16  = (size_t)((char*)(xh + (size_t)N_NODES * DIM) - (char*)d_ws);
    bool use_bf16 = (ws_size >= need_bf16);

    convert_hist_kernel<<<NCHUNK, 1024, 0, stream>>>(x, xh, col, localH, E, chunk,
                                                     use_bf16 ? n4 : 0);
    chunk_offset_kernel<<<(NB + 255) / 256, 256, 0, stream>>>(localH, bucket_total);
    total_scan_kernel<<<1, 1024, 0, stream>>>(bucket_total, bucket_base);
    binning_kernel<<<NCHUNK, 1024, 0, stream>>>(row, col, localH, bucket_base,
                                                packed, E, chunk);
    if (use_bf16)
        aggregate_bucket_kernel<true><<<NB, 512, 0, stream>>>(x, xh, packed, bucket_base, out);
    else
        aggregate_bucket_kernel<false><<<NB, 512, 0, stream>>>(x, xh, packed, bucket_base, out);
}

// Round 15
// 60.031 us; speedup vs baseline: 7.0354x; 1.1573x over previous
//
#include <hip/hip_runtime.h>

#define N_NODES 50000
#define DIM 64
#define NPB 32                                  // nodes per bucket (dst >> 5)
#define NB 1563                                 // ceil(50000/32)
#define NCHUNK 128                              // edge chunks (= binning blocks)
#define CAPB 1024                               // fixed packed capacity per bucket
#define CAP 1024                                // aggregate per-iteration LDS capacity

typedef unsigned short ushort_t;

__device__ __forceinline__ ushort_t f32_to_bf16(float f) {
    unsigned u = __float_as_uint(f);
    u += 0x7FFFu + ((u >> 16) & 1u);            // round-to-nearest-even
    return (ushort_t)(u >> 16);
}

__device__ __forceinline__ void acc_pair(float& a0, float& a1, unsigned u) {
    a0 += __uint_as_float(u << 16);             // low bf16  (even dim)
    a1 += __uint_as_float(u & 0xFFFF0000u);     // high bf16 (odd dim)
}

// ---- K1: fused convert(x->bf16) + per-chunk bucket histogram ----
__global__ void convert_hist_kernel(const float* __restrict__ xf,
                                    ushort_t* __restrict__ xh,
                                    const int* __restrict__ col,
                                    int* __restrict__ localH,
                                    int E, int chunk, int n4) {
    __shared__ int h[NB];
    int c = blockIdx.x;
    int tid = threadIdx.x;
    for (int i = c * blockDim.x + tid; i < n4; i += gridDim.x * blockDim.x) {
        float4 v = *reinterpret_cast<const float4*>(xf + (size_t)i * 4);
        ushort4 hh;
        hh.x = f32_to_bf16(v.x);
        hh.y = f32_to_bf16(v.y);
        hh.z = f32_to_bf16(v.z);
        hh.w = f32_to_bf16(v.w);
        *reinterpret_cast<ushort4*>(xh + (size_t)i * 4) = hh;
    }
    for (int b = tid; b < NB; b += blockDim.x) h[b] = 0;
    __syncthreads();
    int beg = c * chunk, end = min(beg + chunk, E);
    int nfull = (end - beg) >> 2;
    for (int g = tid; g < nfull; g += blockDim.x) {
        int4 c4 = *reinterpret_cast<const int4*>(col + beg + g * 4);
        atomicAdd(&h[c4.x >> 5], 1);
        atomicAdd(&h[c4.y >> 5], 1);
        atomicAdd(&h[c4.z >> 5], 1);
        atomicAdd(&h[c4.w >> 5], 1);
    }
    for (int e = beg + nfull * 4 + tid; e < end; e += blockDim.x)
        atomicAdd(&h[col[e] >> 5], 1);
    __syncthreads();
    for (int b = tid; b < NB; b += blockDim.x)
        localH[(size_t)c * NB + b] = h[b];
}

// ---- K2: per-bucket prefix over chunks (wave per bucket, in-place) + totals ----
__global__ void chunk_offset_kernel(int* __restrict__ localH,
                                    int* __restrict__ bucket_total) {
    int b = blockIdx.x;
    int lane = threadIdx.x;                     // single wave per bucket
    int running = 0;
    #pragma unroll
    for (int c0 = 0; c0 < NCHUNK; c0 += 64) {
        int c = c0 + lane;
        int v = localH[(size_t)c * NB + b];
        int incl = v;
        #pragma unroll
        for (int ofs = 1; ofs < 64; ofs <<= 1) {
            int t = __shfl_up(incl, ofs);
            if (lane >= ofs) incl += t;
        }
        localH[(size_t)c * NB + b] = running + incl - v;
        running += __shfl(incl, 63);
    }
    if (lane == 0) bucket_total[b] = running;
}

// ---- K3: binning scatter into FIXED per-bucket regions (no global scan) ----
__global__ void binning_kernel(const int* __restrict__ row,
                               const int* __restrict__ col,
                               const int* __restrict__ localH,
                               unsigned* __restrict__ packed,
                               int E, int chunk) {
    __shared__ int cursor[NB];
    int c = blockIdx.x;
    int tid = threadIdx.x;
    for (int b = tid; b < NB; b += blockDim.x)
        cursor[b] = b * CAPB + localH[(size_t)c * NB + b];
    __syncthreads();
    int beg = c * chunk, end = min(beg + chunk, E);
    int nfull = (end - beg) >> 2;
    for (int g = tid; g < nfull; g += blockDim.x) {
        int e = beg + g * 4;
        int4 d4 = *reinterpret_cast<const int4*>(col + e);
        int4 s4 = *reinterpret_cast<const int4*>(row + e);
        int p0 = atomicAdd(&cursor[d4.x >> 5], 1);
        packed[p0] = (unsigned)s4.x | ((unsigned)(d4.x & 31) << 16);
        int p1 = atomicAdd(&cursor[d4.y >> 5], 1);
        packed[p1] = (unsigned)s4.y | ((unsigned)(d4.y & 31) << 16);
        int p2 = atomicAdd(&cursor[d4.z >> 5], 1);
        packed[p2] = (unsigned)s4.z | ((unsigned)(d4.z & 31) << 16);
        int p3 = atomicAdd(&cursor[d4.w >> 5], 1);
        packed[p3] = (unsigned)s4.w | ((unsigned)(d4.w & 31) << 16);
    }
    for (int e = beg + nfull * 4 + tid; e < end; e += blockDim.x) {
        int d = col[e];
        int p = atomicAdd(&cursor[d >> 5], 1);
        packed[p] = (unsigned)row[e] | ((unsigned)(d & 31) << 16);
    }
}

// ---- K4: per-bucket counting sort (LDS) + 8-lane/row gather + mean ----
// 512 threads = 8 waves; wave wv owns nodes [wv*4, wv*4+4).
// Lane split: g8 = lane>>3 (row slot 0..7), o = lane&7 (dim octet).
// One uint4 load = 8 bf16 dims of one row; 8 rows per instruction per wave.
template <bool BF16>
__global__ __launch_bounds__(512)
void aggregate_bucket_kernel(const float* __restrict__ xf,
                             const ushort_t* __restrict__ xh,
                             const unsigned* __restrict__ packed,
                             const int* __restrict__ bucket_total,
                             float* __restrict__ out) {
    __shared__ unsigned buf[CAP];
    __shared__ unsigned short srcs[CAP];
    __shared__ int hist[NPB];
    __shared__ int segoff[NPB];
    __shared__ int cursor[NPB];
    __shared__ int cnt_tot[NPB];

    int b = blockIdx.x;
    int tid = threadIdx.x;                      // 0..511
    int lane = tid & 63;
    int wv = tid >> 6;                          // wave 0..7
    int g8 = lane >> 3;                         // row slot 0..7
    int o = lane & 7;                           // dim octet (dims o*8 .. o*8+7)
    int seg_beg = b * CAPB;
    int seg_end = seg_beg + bucket_total[b];
    int node_base = b * NPB;
    int nnodes = min(NPB, N_NODES - node_base);

    float acc[4][8];
    #pragma unroll
    for (int r = 0; r < 4; ++r)
        #pragma unroll
        for (int k = 0; k < 8; ++k) acc[r][k] = 0.0f;
    if (tid < NPB) cnt_tot[tid] = 0;

    for (int cs = seg_beg; cs < seg_end; cs += CAP) {
        int m = min(CAP, seg_end - cs);
        __syncthreads();
        if (tid < NPB) hist[tid] = 0;
        __syncthreads();
        for (int i = tid; i < m; i += 512) {
            unsigned v = packed[cs + i];
            buf[i] = v;
            atomicAdd(&hist[v >> 16], 1);
        }
        __syncthreads();
        if (tid < NPB) {                        // lanes 0..31 of wave 0: scan 32 bins
            int v = hist[tid];
            int incl = v;
            #pragma unroll
            for (int ofs = 1; ofs < 32; ofs <<= 1) {
                int t = __shfl_up(incl, ofs);
                if (lane >= ofs) incl += t;
            }
            segoff[tid] = incl - v;
            cursor[tid] = incl - v;
            cnt_tot[tid] += v;
        }
        __syncthreads();
        for (int i = tid; i < m; i += 512) {
            unsigned v = buf[i];
            int p = atomicAdd(&cursor[v >> 16], 1);
            srcs[p] = (unsigned short)(v & 0xFFFF);
        }
        __syncthreads();
        #pragma unroll
        for (int r = 0; r < 4; ++r) {
            int ln = wv * 4 + r;
            int st = segoff[ln];
            int len = hist[ln];
            int j = 0;
            for (; j + 16 <= len; j += 16) {    // 16 rows in flight per wave
                int s0 = srcs[st + j + g8];
                int s1 = srcs[st + j + 8 + g8];
                if (BF16) {
                    uint4 a0 = *reinterpret_cast<const uint4*>(xh + (size_t)s0 * DIM + o * 8);
                    uint4 a1 = *reinterpret_cast<const uint4*>(xh + (size_t)s1 * DIM + o * 8);
                    acc_pair(acc[r][0], acc[r][1], a0.x);
                    acc_pair(acc[r][2], acc[r][3], a0.y);
                    acc_pair(acc[r][4], acc[r][5], a0.z);
                    acc_pair(acc[r][6], acc[r][7], a0.w);
                    acc_pair(acc[r][0], acc[r][1], a1.x);
                    acc_pair(acc[r][2], acc[r][3], a1.y);
                    acc_pair(acc[r][4], acc[r][5], a1.z);
                    acc_pair(acc[r][6], acc[r][7], a1.w);
                } else {
                    float4 u0 = *reinterpret_cast<const float4*>(xf + (size_t)s0 * DIM + o * 8);
                    float4 u1 = *reinterpret_cast<const float4*>(xf + (size_t)s0 * DIM + o * 8 + 4);
                    float4 u2 = *reinterpret_cast<const float4*>(xf + (size_t)s1 * DIM + o * 8);
                    float4 u3 = *reinterpret_cast<const float4*>(xf + (size_t)s1 * DIM + o * 8 + 4);
                    acc[r][0] += u0.x + u2.x; acc[r][1] += u0.y + u2.y;
                    acc[r][2] += u0.z + u2.z; acc[r][3] += u0.w + u2.w;
                    acc[r][4] += u1.x + u3.x; acc[r][5] += u1.y + u3.y;
                    acc[r][6] += u1.z + u3.z; acc[r][7] += u1.w + u3.w;
                }
            }
            for (; j < len; j += 8) {
                if (j + g8 < len) {
                    int s = srcs[st + j + g8];
                    if (BF16) {
                        uint4 a0 = *reinterpret_cast<const uint4*>(xh + (size_t)s * DIM + o * 8);
                        acc_pair(acc[r][0], acc[r][1], a0.x);
                        acc_pair(acc[r][2], acc[r][3], a0.y);
                        acc_pair(acc[r][4], acc[r][5], a0.z);
                        acc_pair(acc[r][6], acc[r][7], a0.w);
                    } else {
                        float4 u0 = *reinterpret_cast<const float4*>(xf + (size_t)s * DIM + o * 8);
                        float4 u1 = *reinterpret_cast<const float4*>(xf + (size_t)s * DIM + o * 8 + 4);
                        acc[r][0] += u0.x; acc[r][1] += u0.y;
                        acc[r][2] += u0.z; acc[r][3] += u0.w;
                        acc[r][4] += u1.x; acc[r][5] += u1.y;
                        acc[r][6] += u1.z; acc[r][7] += u1.w;
                    }
                }
            }
        }
    }
    __syncthreads();
    // reduce across row slots (xor 8,16,32) + mean + store
    #pragma unroll
    for (int r = 0; r < 4; ++r) {
        int ln = wv * 4 + r;
        #pragma unroll
        for (int k = 0; k < 8; ++k) {
            acc[r][k] += __shfl_xor(acc[r][k], 8);
            acc[r][k] += __shfl_xor(acc[r][k], 16);
            acc[r][k] += __shfl_xor(acc[r][k], 32);
        }
        if (g8 == 0 && ln < nnodes) {
            int c = cnt_tot[ln];
            float inv = (c > 0) ? 1.0f / (float)c : 0.0f;
            float4 lo = make_float4(acc[r][0] * inv, acc[r][1] * inv,
                                    acc[r][2] * inv, acc[r][3] * inv);
            float4 hi = make_float4(acc[r][4] * inv, acc[r][5] * inv,
                                    acc[r][6] * inv, acc[r][7] * inv);
            float* op = out + (size_t)(node_base + ln) * DIM + o * 8;
            *reinterpret_cast<float4*>(op) = lo;
            *reinterpret_cast<float4*>(op + 4) = hi;
        }
    }
}

extern "C" void kernel_launch(void* const* d_in, const int* in_sizes, int n_in,
                              void* d_out, int out_size, void* d_ws, size_t ws_size,
                              hipStream_t stream) {
    const float* x = (const float*)d_in[0];
    const int* edge_index = (const int*)d_in[1];  // [2, E] flat: row then col
    int E = in_sizes[1] / 2;
    const int* row = edge_index;
    const int* col = edge_index + E;
    float* out = (float*)d_out;

    int chunk = (((E + NCHUNK - 1) / NCHUNK) + 3) & ~3;   // multiple of 4
    int n4 = N_NODES * DIM / 4;

    // ws: bucket_total 1568 | localH NCHUNK*NB | packed NB*CAPB | xh N*DIM bf16
    int* bucket_total = (int*)d_ws;
    int* localH       = bucket_total + 1568;
    unsigned* packed  = (unsigned*)(localH + (size_t)NCHUNK * NB);
    ushort_t* xh      = (ushort_t*)(packed + (size_t)NB * CAPB);
    size_t need_bf16  = (size_t)((char*)(xh + (size_t)N_NODES * DIM) - (char*)d_ws);
    bool use_bf16 = (ws_size >= need_bf16);

    convert_hist_kernel<<<NCHUNK, 1024, 0, stream>>>(x, xh, col, localH, E, chunk,
                                                     use_bf16 ? n4 : 0);
    chunk_offset_kernel<<<NB, 64, 0, stream>>>(localH, bucket_total);
    binning_kernel<<<NCHUNK, 1024, 0, stream>>>(row, col, localH, packed, E, chunk);
    if (use_bf16)
        aggregate_bucket_kernel<true><<<NB, 512, 0, stream>>>(x, xh, packed, bucket_total, out);
    else
        aggregate_bucket_kernel<false><<<NB, 512, 0, stream>>>(x, xh, packed, bucket_total, out);
}

// Round 16
// 58.412 us; speedup vs baseline: 7.2304x; 1.0277x over previous
//
#include <hip/hip_runtime.h>

#define N_NODES 50000
#define DIM 64
#define NPB 32                                  // nodes per bucket (dst >> 5)
#define NB 1563                                 // ceil(50000/32)
#define NCHUNK 256                              // edge chunks (= binning blocks)
#define CAPB 1024                               // fixed packed capacity per bucket
#define CAP 1024                                // aggregate per-iteration LDS capacity

typedef unsigned short ushort_t;

__device__ __forceinline__ ushort_t f32_to_bf16(float f) {
    unsigned u = __float_as_uint(f);
    u += 0x7FFFu + ((u >> 16) & 1u);            // round-to-nearest-even
    return (ushort_t)(u >> 16);
}

__device__ __forceinline__ void acc_pair(float& a0, float& a1, unsigned u) {
    a0 += __uint_as_float(u << 16);             // low bf16  (even dim)
    a1 += __uint_as_float(u & 0xFFFF0000u);     // high bf16 (odd dim)
}

// ---- K0: convert x->bf16 + init per-bucket cursors to region bases ----
__global__ void convert_init_kernel(const float* __restrict__ xf,
                                    ushort_t* __restrict__ xh,
                                    int* __restrict__ cursor, int n4) {
    int gt = blockIdx.x * blockDim.x + threadIdx.x;
    if (gt <= NB) cursor[gt] = gt * CAPB;       // [0..NB] (NB entry = end sentinel base)
    for (int i = gt; i < n4; i += gridDim.x * blockDim.x) {
        float4 v = *reinterpret_cast<const float4*>(xf + (size_t)i * 4);
        ushort4 hh;
        hh.x = f32_to_bf16(v.x);
        hh.y = f32_to_bf16(v.y);
        hh.z = f32_to_bf16(v.z);
        hh.w = f32_to_bf16(v.w);
        *reinterpret_cast<ushort4*>(xh + (size_t)i * 4) = hh;
    }
}

// ---- K1: fused hist + region-reserve + binning scatter ----
// Pass 1: LDS histogram of this block's chunk. Reserve: one global atomicAdd
// per touched bucket. Pass 2: scatter via LDS-local cursors (col re-read = L2 hit).
__global__ void binning_kernel(const int* __restrict__ row,
                               const int* __restrict__ col,
                               int* __restrict__ cursor,
                               unsigned* __restrict__ packed,
                               int E, int chunk) {
    __shared__ int h[NB];
    __shared__ int lcur[NB];
    int c = blockIdx.x;
    int tid = threadIdx.x;
    for (int b = tid; b < NB; b += blockDim.x) h[b] = 0;
    __syncthreads();
    int beg = c * chunk, end = min(beg + chunk, E);
    int nfull = (end - beg) >> 2;
    for (int g = tid; g < nfull; g += blockDim.x) {
        int4 c4 = *reinterpret_cast<const int4*>(col + beg + g * 4);
        atomicAdd(&h[c4.x >> 5], 1);
        atomicAdd(&h[c4.y >> 5], 1);
        atomicAdd(&h[c4.z >> 5], 1);
        atomicAdd(&h[c4.w >> 5], 1);
    }
    for (int e = beg + nfull * 4 + tid; e < end; e += blockDim.x)
        atomicAdd(&h[col[e] >> 5], 1);
    __syncthreads();
    for (int b = tid; b < NB; b += blockDim.x) {
        int v = h[b];
        lcur[b] = (v > 0) ? atomicAdd(&cursor[b], v) : 0;   // reserve block slice
    }
    __syncthreads();
    for (int g = tid; g < nfull; g += blockDim.x) {
        int e = beg + g * 4;
        int4 d4 = *reinterpret_cast<const int4*>(col + e);
        int4 s4 = *reinterpret_cast<const int4*>(row + e);
        int p0 = atomicAdd(&lcur[d4.x >> 5], 1);
        packed[p0] = (unsigned)s4.x | ((unsigned)(d4.x & 31) << 16);
        int p1 = atomicAdd(&lcur[d4.y >> 5], 1);
        packed[p1] = (unsigned)s4.y | ((unsigned)(d4.y & 31) << 16);
        int p2 = atomicAdd(&lcur[d4.z >> 5], 1);
        packed[p2] = (unsigned)s4.z | ((unsigned)(d4.z & 31) << 16);
        int p3 = atomicAdd(&lcur[d4.w >> 5], 1);
        packed[p3] = (unsigned)s4.w | ((unsigned)(d4.w & 31) << 16);
    }
    for (int e = beg + nfull * 4 + tid; e < end; e += blockDim.x) {
        int d = col[e];
        int p = atomicAdd(&lcur[d >> 5], 1);
        packed[p] = (unsigned)row[e] | ((unsigned)(d & 31) << 16);
    }
}

// ---- K2: per-bucket counting sort (LDS) + 8-lane/row gather + mean ----
// 512 threads = 8 waves; wave wv owns nodes [wv*4, wv*4+4).
// Lane split: g8 = lane>>3 (row slot 0..7), o = lane&7 (dim octet).
template <bool BF16>
__global__ __launch_bounds__(512)
void aggregate_bucket_kernel(const float* __restrict__ xf,
                             const ushort_t* __restrict__ xh,
                             const unsigned* __restrict__ packed,
                             const int* __restrict__ cursor,
                             float* __restrict__ out) {
    __shared__ unsigned buf[CAP];
    __shared__ unsigned short srcs[CAP];
    __shared__ int hist[NPB];
    __shared__ int segoff[NPB];
    __shared__ int lcur[NPB];
    __shared__ int cnt_tot[NPB];

    int b = blockIdx.x;
    int tid = threadIdx.x;                      // 0..511
    int lane = tid & 63;
    int wv = tid >> 6;                          // wave 0..7
    int g8 = lane >> 3;                         // row slot 0..7
    int o = lane & 7;                           // dim octet (dims o*8 .. o*8+7)
    int seg_beg = b * CAPB;
    int seg_end = cursor[b];                    // base + total after binning
    int node_base = b * NPB;
    int nnodes = min(NPB, N_NODES - node_base);

    float acc[4][8];
    #pragma unroll
    for (int r = 0; r < 4; ++r)
        #pragma unroll
        for (int k = 0; k < 8; ++k) acc[r][k] = 0.0f;
    if (tid < NPB) cnt_tot[tid] = 0;

    for (int cs = seg_beg; cs < seg_end; cs += CAP) {
        int m = min(CAP, seg_end - cs);
        __syncthreads();
        if (tid < NPB) hist[tid] = 0;
        __syncthreads();
        for (int i = tid; i < m; i += 512) {
            unsigned v = packed[cs + i];
            buf[i] = v;
            atomicAdd(&hist[v >> 16], 1);
        }
        __syncthreads();
        if (tid < NPB) {                        // lanes 0..31 of wave 0: scan 32 bins
            int v = hist[tid];
            int incl = v;
            #pragma unroll
            for (int ofs = 1; ofs < 32; ofs <<= 1) {
                int t = __shfl_up(incl, ofs);
                if (lane >= ofs) incl += t;
            }
            segoff[tid] = incl - v;
            lcur[tid] = incl - v;
            cnt_tot[tid] += v;
        }
        __syncthreads();
        for (int i = tid; i < m; i += 512) {
            unsigned v = buf[i];
            int p = atomicAdd(&lcur[v >> 16], 1);
            srcs[p] = (unsigned short)(v & 0xFFFF);
        }
        __syncthreads();
        #pragma unroll
        for (int r = 0; r < 4; ++r) {
            int ln = wv * 4 + r;
            int st = segoff[ln];
            int len = hist[ln];
            int j = 0;
            for (; j + 16 <= len; j += 16) {    // 16 rows in flight per wave
                int s0 = srcs[st + j + g8];
                int s1 = srcs[st + j + 8 + g8];
                if (BF16) {
                    uint4 a0 = *reinterpret_cast<const uint4*>(xh + (size_t)s0 * DIM + o * 8);
                    uint4 a1 = *reinterpret_cast<const uint4*>(xh + (size_t)s1 * DIM + o * 8);
                    acc_pair(acc[r][0], acc[r][1], a0.x);
                    acc_pair(acc[r][2], acc[r][3], a0.y);
                    acc_pair(acc[r][4], acc[r][5], a0.z);
                    acc_pair(acc[r][6], acc[r][7], a0.w);
                    acc_pair(acc[r][0], acc[r][1], a1.x);
                    acc_pair(acc[r][2], acc[r][3], a1.y);
                    acc_pair(acc[r][4], acc[r][5], a1.z);
                    acc_pair(acc[r][6], acc[r][7], a1.w);
                } else {
                    float4 u0 = *reinterpret_cast<const float4*>(xf + (size_t)s0 * DIM + o * 8);
                    float4 u1 = *reinterpret_cast<const float4*>(xf + (size_t)s0 * DIM + o * 8 + 4);
                    float4 u2 = *reinterpret_cast<const float4*>(xf + (size_t)s1 * DIM + o * 8);
                    float4 u3 = *reinterpret_cast<const float4*>(xf + (size_t)s1 * DIM + o * 8 + 4);
                    acc[r][0] += u0.x + u2.x; acc[r][1] += u0.y + u2.y;
                    acc[r][2] += u0.z + u2.z; acc[r][3] += u0.w + u2.w;
                    acc[r][4] += u1.x + u3.x; acc[r][5] += u1.y + u3.y;
                    acc[r][6] += u1.z + u3.z; acc[r][7] += u1.w + u3.w;
                }
            }
            for (; j < len; j += 8) {
                if (j + g8 < len) {
                    int s = srcs[st + j + g8];
                    if (BF16) {
                        uint4 a0 = *reinterpret_cast<const uint4*>(xh + (size_t)s * DIM + o * 8);
                        acc_pair(acc[r][0], acc[r][1], a0.x);
                        acc_pair(acc[r][2], acc[r][3], a0.y);
                        acc_pair(acc[r][4], acc[r][5], a0.z);
                        acc_pair(acc[r][6], acc[r][7], a0.w);
                    } else {
                        float4 u0 = *reinterpret_cast<const float4*>(xf + (size_t)s * DIM + o * 8);
                        float4 u1 = *reinterpret_cast<const float4*>(xf + (size_t)s * DIM + o * 8 + 4);
                        acc[r][0] += u0.x; acc[r][1] += u0.y;
                        acc[r][2] += u0.z; acc[r][3] += u0.w;
                        acc[r][4] += u1.x; acc[r][5] += u1.y;
                        acc[r][6] += u1.z; acc[r][7] += u1.w;
                    }
                }
            }
        }
    }
    __syncthreads();
    // reduce across row slots (xor 8,16,32) + mean + store
    #pragma unroll
    for (int r = 0; r < 4; ++r) {
        int ln = wv * 4 + r;
        #pragma unroll
        for (int k = 0; k < 8; ++k) {
            acc[r][k] += __shfl_xor(acc[r][k], 8);
            acc[r][k] += __shfl_xor(acc[r][k], 16);
            acc[r][k] += __shfl_xor(acc[r][k], 32);
        }
        if (g8 == 0 && ln < nnodes) {
            int c = cnt_tot[ln];
            float inv = (c > 0) ? 1.0f / (float)c : 0.0f;
            float4 lo = make_float4(acc[r][0] * inv, acc[r][1] * inv,
                                    acc[r][2] * inv, acc[r][3] * inv);
            float4 hi = make_float4(acc[r][4] * inv, acc[r][5] * inv,
                                    acc[r][6] * inv, acc[r][7] * inv);
            float* op = out + (size_t)(node_base + ln) * DIM + o * 8;
            *reinterpret_cast<float4*>(op) = lo;
            *reinterpret_cast<float4*>(op + 4) = hi;
        }
    }
}

extern "C" void kernel_launch(void* const* d_in, const int* in_sizes, int n_in,
                              void* d_out, int out_size, void* d_ws, size_t ws_size,
                              hipStream_t stream) {
    const float* x = (const float*)d_in[0];
    const int* edge_index = (const int*)d_in[1];  // [2, E] flat: row then col
    int E = in_sizes[1] / 2;
    const int* row = edge_index;
    const int* col = edge_index + E;
    float* out = (float*)d_out;

    int chunk = (((E + NCHUNK - 1) / NCHUNK) + 3) & ~3;   // multiple of 4
    int n4 = N_NODES * DIM / 4;

    // ws: cursor 1568 | packed NB*CAPB | xh N*DIM bf16
    int* cursor      = (int*)d_ws;
    unsigned* packed = (unsigned*)(cursor + 1568);
    ushort_t* xh     = (ushort_t*)(packed + (size_t)NB * CAPB);
    size_t need_bf16 = (size_t)((char*)(xh + (size_t)N_NODES * DIM) - (char*)d_ws);
    bool use_bf16 = (ws_size >= need_bf16);

    convert_init_kernel<<<256, 1024, 0, stream>>>(x, xh, cursor, use_bf16 ? n4 : 0);
    binning_kernel<<<NCHUNK, 1024, 0, stream>>>(row, col, cursor, packed, E, chunk);
    if (use_bf16)
        aggregate_bucket_kernel<true><<<NB, 512, 0, stream>>>(x, xh, packed, cursor, out);
    else
        aggregate_bucket_kernel<false><<<NB, 512, 0, stream>>>(x, xh, packed, cursor, out);
}

// Round 17
// 56.948 us; speedup vs baseline: 7.4163x; 1.0257x over previous
//
#include <hip/hip_runtime.h>

#define N_NODES 50000
#define DIM 64
#define NPB 32                                  // nodes per bucket (dst >> 5)
#define NB 1563                                 // ceil(50000/32)
#define NCHUNK 256                              // edge chunks (= binning blocks)
#define CAPB 1024                               // fixed packed capacity per bucket
#define CAP 1024                                // aggregate per-iteration LDS capacity

typedef unsigned short ushort_t;

__device__ __forceinline__ ushort_t f32_to_bf16(float f) {
    unsigned u = __float_as_uint(f);
    u += 0x7FFFu + ((u >> 16) & 1u);            // round-to-nearest-even
    return (ushort_t)(u >> 16);
}

__device__ __forceinline__ void acc_pair(float& a0, float& a1, unsigned u) {
    a0 += __uint_as_float(u << 16);             // low bf16  (even dim)
    a1 += __uint_as_float(u & 0xFFFF0000u);     // high bf16 (odd dim)
}

// ---- K0: init per-bucket cursors to region bases (tiny) ----
__global__ void init_cursor_kernel(int* __restrict__ cursor) {
    int t = blockIdx.x * blockDim.x + threadIdx.x;
    if (t <= NB) cursor[t] = t * CAPB;
}

// ---- K1: fused convert(x->bf16) + hist + region-reserve + binning scatter ----
__global__ void binning_kernel(const float* __restrict__ xf,
                               ushort_t* __restrict__ xh,
                               const int* __restrict__ row,
                               const int* __restrict__ col,
                               int* __restrict__ cursor,
                               unsigned* __restrict__ packed,
                               int E, int chunk, int n4) {
    __shared__ int h[NB];
    __shared__ int lcur[NB];
    int c = blockIdx.x;
    int tid = threadIdx.x;
    // convert: grid-stride (independent of binning phases)
    for (int i = c * blockDim.x + tid; i < n4; i += gridDim.x * blockDim.x) {
        float4 v = *reinterpret_cast<const float4*>(xf + (size_t)i * 4);
        ushort4 hh;
        hh.x = f32_to_bf16(v.x);
        hh.y = f32_to_bf16(v.y);
        hh.z = f32_to_bf16(v.z);
        hh.w = f32_to_bf16(v.w);
        *reinterpret_cast<ushort4*>(xh + (size_t)i * 4) = hh;
    }
    for (int b = tid; b < NB; b += blockDim.x) h[b] = 0;
    __syncthreads();
    int beg = c * chunk, end = min(beg + chunk, E);
    int nfull = (end - beg) >> 2;
    for (int g = tid; g < nfull; g += blockDim.x) {
        int4 c4 = *reinterpret_cast<const int4*>(col + beg + g * 4);
        atomicAdd(&h[c4.x >> 5], 1);
        atomicAdd(&h[c4.y >> 5], 1);
        atomicAdd(&h[c4.z >> 5], 1);
        atomicAdd(&h[c4.w >> 5], 1);
    }
    for (int e = beg + nfull * 4 + tid; e < end; e += blockDim.x)
        atomicAdd(&h[col[e] >> 5], 1);
    __syncthreads();
    for (int b = tid; b < NB; b += blockDim.x) {
        int v = h[b];
        lcur[b] = (v > 0) ? atomicAdd(&cursor[b], v) : 0;   // reserve block slice
    }
    __syncthreads();
    for (int g = tid; g < nfull; g += blockDim.x) {
        int e = beg + g * 4;
        int4 d4 = *reinterpret_cast<const int4*>(col + e);
        int4 s4 = *reinterpret_cast<const int4*>(row + e);
        int p0 = atomicAdd(&lcur[d4.x >> 5], 1);
        packed[p0] = (unsigned)s4.x | ((unsigned)(d4.x & 31) << 16);
        int p1 = atomicAdd(&lcur[d4.y >> 5], 1);
        packed[p1] = (unsigned)s4.y | ((unsigned)(d4.y & 31) << 16);
        int p2 = atomicAdd(&lcur[d4.z >> 5], 1);
        packed[p2] = (unsigned)s4.z | ((unsigned)(d4.z & 31) << 16);
        int p3 = atomicAdd(&lcur[d4.w >> 5], 1);
        packed[p3] = (unsigned)s4.w | ((unsigned)(d4.w & 31) << 16);
    }
    for (int e = beg + nfull * 4 + tid; e < end; e += blockDim.x) {
        int d = col[e];
        int p = atomicAdd(&lcur[d >> 5], 1);
        packed[p] = (unsigned)row[e] | ((unsigned)(d & 31) << 16);
    }
}

// ---- K2: per-bucket counting sort (no LDS buf; packed read twice from L2)
//      + 8-lane/row gather + mean ----
template <bool BF16>
__global__ __launch_bounds__(512)
void aggregate_bucket_kernel(const float* __restrict__ xf,
                             const ushort_t* __restrict__ xh,
                             const unsigned* __restrict__ packed,
                             const int* __restrict__ cursor,
                             float* __restrict__ out) {
    __shared__ unsigned short srcs[CAP];
    __shared__ int hist[NPB];
    __shared__ int segoff[NPB];
    __shared__ int lcur[NPB];
    __shared__ int cnt_tot[NPB];

    int b = blockIdx.x;
    int tid = threadIdx.x;                      // 0..511
    int lane = tid & 63;
    int wv = tid >> 6;                          // wave 0..7
    int g8 = lane >> 3;                         // row slot 0..7
    int o = lane & 7;                           // dim octet (dims o*8 .. o*8+7)
    int seg_beg = b * CAPB;
    int seg_end = cursor[b];                    // base + total after binning
    int node_base = b * NPB;
    int nnodes = min(NPB, N_NODES - node_base);

    float acc[4][8];
    #pragma unroll
    for (int r = 0; r < 4; ++r)
        #pragma unroll
        for (int k = 0; k < 8; ++k) acc[r][k] = 0.0f;
    if (tid < NPB) cnt_tot[tid] = 0;

    for (int cs = seg_beg; cs < seg_end; cs += CAP) {
        int m = min(CAP, seg_end - cs);
        __syncthreads();
        if (tid < NPB) hist[tid] = 0;
        __syncthreads();
        {   // pass 1: histogram, uint4-vectorized (cs is 1024-aligned)
            int nf = m >> 2;
            const uint4* p4 = reinterpret_cast<const uint4*>(packed + cs);
            for (int i = tid; i < nf; i += 512) {
                uint4 v = p4[i];
                atomicAdd(&hist[v.x >> 16], 1);
                atomicAdd(&hist[v.y >> 16], 1);
                atomicAdd(&hist[v.z >> 16], 1);
                atomicAdd(&hist[v.w >> 16], 1);
            }
            for (int i = nf * 4 + tid; i < m; i += 512)
                atomicAdd(&hist[packed[cs + i] >> 16], 1);
        }
        __syncthreads();
        if (tid < NPB) {                        // lanes 0..31 of wave 0: scan 32 bins
            int v = hist[tid];
            int incl = v;
            #pragma unroll
            for (int ofs = 1; ofs < 32; ofs <<= 1) {
                int t = __shfl_up(incl, ofs);
                if (lane >= ofs) incl += t;
            }
            segoff[tid] = incl - v;
            lcur[tid] = incl - v;
            cnt_tot[tid] += v;
        }
        __syncthreads();
        for (int i = tid; i < m; i += 512) {    // pass 2: scatter (packed L2-hit)
            unsigned v = packed[cs + i];
            int p = atomicAdd(&lcur[v >> 16], 1);
            srcs[p] = (unsigned short)(v & 0xFFFF);
        }
        __syncthreads();
        #pragma unroll
        for (int r = 0; r < 4; ++r) {
            int ln = wv * 4 + r;
            int st = segoff[ln];
            int len = hist[ln];
            int j = 0;
            for (; j + 16 <= len; j += 16) {    // 16 rows in flight per wave
                int s0 = srcs[st + j + g8];
                int s1 = srcs[st + j + 8 + g8];
                if (BF16) {
                    uint4 a0 = *reinterpret_cast<const uint4*>(xh + (size_t)s0 * DIM + o * 8);
                    uint4 a1 = *reinterpret_cast<const uint4*>(xh + (size_t)s1 * DIM + o * 8);
                    acc_pair(acc[r][0], acc[r][1], a0.x);
                    acc_pair(acc[r][2], acc[r][3], a0.y);
                    acc_pair(acc[r][4], acc[r][5], a0.z);
                    acc_pair(acc[r][6], acc[r][7], a0.w);
                    acc_pair(acc[r][0], acc[r][1], a1.x);
                    acc_pair(acc[r][2], acc[r][3], a1.y);
                    acc_pair(acc[r][4], acc[r][5], a1.z);
                    acc_pair(acc[r][6], acc[r][7], a1.w);
                } else {
                    float4 u0 = *reinterpret_cast<const float4*>(xf + (size_t)s0 * DIM + o * 8);
                    float4 u1 = *reinterpret_cast<const float4*>(xf + (size_t)s0 * DIM + o * 8 + 4);
                    float4 u2 = *reinterpret_cast<const float4*>(xf + (size_t)s1 * DIM + o * 8);
                    float4 u3 = *reinterpret_cast<const float4*>(xf + (size_t)s1 * DIM + o * 8 + 4);
                    acc[r][0] += u0.x + u2.x; acc[r][1] += u0.y + u2.y;
                    acc[r][2] += u0.z + u2.z; acc[r][3] += u0.w + u2.w;
                    acc[r][4] += u1.x + u3.x; acc[r][5] += u1.y + u3.y;
                    acc[r][6] += u1.z + u3.z; acc[r][7] += u1.w + u3.w;
                }
            }
            for (; j < len; j += 8) {
                if (j + g8 < len) {
                    int s = srcs[st + j + g8];
                    if (BF16) {
                        uint4 a0 = *reinterpret_cast<const uint4*>(xh + (size_t)s * DIM + o * 8);
                        acc_pair(acc[r][0], acc[r][1], a0.x);
                        acc_pair(acc[r][2], acc[r][3], a0.y);
                        acc_pair(acc[r][4], acc[r][5], a0.z);
                        acc_pair(acc[r][6], acc[r][7], a0.w);
                    } else {
                        float4 u0 = *reinterpret_cast<const float4*>(xf + (size_t)s * DIM + o * 8);
                        float4 u1 = *reinterpret_cast<const float4*>(xf + (size_t)s * DIM + o * 8 + 4);
                        acc[r][0] += u0.x; acc[r][1] += u0.y;
                        acc[r][2] += u0.z; acc[r][3] += u0.w;
                        acc[r][4] += u1.x; acc[r][5] += u1.y;
                        acc[r][6] += u1.z; acc[r][7] += u1.w;
                    }
                }
            }
        }
    }
    __syncthreads();
    // reduce across row slots (xor 8,16,32) + mean + store
    #pragma unroll
    for (int r = 0; r < 4; ++r) {
        int ln = wv * 4 + r;
        #pragma unroll
        for (int k = 0; k < 8; ++k) {
            acc[r][k] += __shfl_xor(acc[r][k], 8);
            acc[r][k] += __shfl_xor(acc[r][k], 16);
            acc[r][k] += __shfl_xor(acc[r][k], 32);
        }
        if (g8 == 0 && ln < nnodes) {
            int c = cnt_tot[ln];
            float inv = (c > 0) ? 1.0f / (float)c : 0.0f;
            float4 lo = make_float4(acc[r][0] * inv, acc[r][1] * inv,
                                    acc[r][2] * inv, acc[r][3] * inv);
            float4 hi = make_float4(acc[r][4] * inv, acc[r][5] * inv,
                                    acc[r][6] * inv, acc[r][7] * inv);
            float* op = out + (size_t)(node_base + ln) * DIM + o * 8;
            *reinterpret_cast<float4*>(op) = lo;
            *reinterpret_cast<float4*>(op + 4) = hi;
        }
    }
}

extern "C" void kernel_launch(void* const* d_in, const int* in_sizes, int n_in,
                              void* d_out, int out_size, void* d_ws, size_t ws_size,
                              hipStream_t stream) {
    const float* x = (const float*)d_in[0];
    const int* edge_index = (const int*)d_in[1];  // [2, E] flat: row then col
    int E = in_sizes[1] / 2;
    const int* row = edge_index;
    const int* col = edge_index + E;
    float* out = (float*)d_out;

    int chunk = (((E + NCHUNK - 1) / NCHUNK) + 3) & ~3;   // multiple of 4
    int n4 = N_NODES * DIM / 4;

    // ws: cursor 1568 | packed NB*CAPB | xh N*DIM bf16
    int* cursor      = (int*)d_ws;
    unsigned* packed = (unsigned*)(cursor + 1568);
    ushort_t* xh     = (ushort_t*)(packed + (size_t)NB * CAPB);
    size_t need_bf16 = (size_t)((char*)(xh + (size_t)N_NODES * DIM) - (char*)d_ws);
    bool use_bf16 = (ws_size >= need_bf16);

    init_cursor_kernel<<<7, 256, 0, stream>>>(cursor);
    binning_kernel<<<NCHUNK, 1024, 0, stream>>>(x, xh, row, col, cursor, packed,
                                                E, chunk, use_bf16 ? n4 : 0);
    if (use_bf16)
        aggregate_bucket_kernel<true><<<NB, 512, 0, stream>>>(x, xh, packed, cursor, out);
    else
        aggregate_bucket_kernel<false><<<NB, 512, 0, stream>>>(x, xh, packed, cursor, out);
}

// Round 18
// 56.751 us; speedup vs baseline: 7.4421x; 1.0035x over previous
//
#include <hip/hip_runtime.h>

#define N_NODES 50000
#define DIM 64
#define NPB 32                                  // nodes per bucket (dst >> 5)
#define NB 1563                                 // ceil(50000/32)
#define NCHUNK 256                              // edge chunks (= binning blocks)
#define CAPB 1024                               // fixed packed capacity per bucket
#define CAP 1024                                // aggregate per-iteration LDS capacity

typedef unsigned short ushort_t;

__device__ __forceinline__ ushort_t f32_to_bf16(float f) {
    unsigned u = __float_as_uint(f);
    u += 0x7FFFu + ((u >> 16) & 1u);            // round-to-nearest-even
    return (ushort_t)(u >> 16);
}

__device__ __forceinline__ void acc_pair(float& a0, float& a1, unsigned u) {
    a0 += __uint_as_float(u << 16);             // low bf16  (even dim)
    a1 += __uint_as_float(u & 0xFFFF0000u);     // high bf16 (odd dim)
}

// ---- K0: init per-bucket cursors to region bases (tiny) ----
__global__ void init_cursor_kernel(int* __restrict__ cursor) {
    int t = blockIdx.x * blockDim.x + threadIdx.x;
    if (t <= NB) cursor[t] = t * CAPB;
}

// ---- K1: fused convert(x->bf16) + hist + region-reserve + binning scatter ----
__global__ void binning_kernel(const float* __restrict__ xf,
                               ushort_t* __restrict__ xh,
                               const int* __restrict__ row,
                               const int* __restrict__ col,
                               int* __restrict__ cursor,
                               unsigned* __restrict__ packed,
                               int E, int chunk, int n4) {
    __shared__ int h[NB];
    __shared__ int lcur[NB];
    int c = blockIdx.x;
    int tid = threadIdx.x;
    // convert: grid-stride (independent of binning phases)
    for (int i = c * blockDim.x + tid; i < n4; i += gridDim.x * blockDim.x) {
        float4 v = *reinterpret_cast<const float4*>(xf + (size_t)i * 4);
        ushort4 hh;
        hh.x = f32_to_bf16(v.x);
        hh.y = f32_to_bf16(v.y);
        hh.z = f32_to_bf16(v.z);
        hh.w = f32_to_bf16(v.w);
        *reinterpret_cast<ushort4*>(xh + (size_t)i * 4) = hh;
    }
    for (int b = tid; b < NB; b += blockDim.x) h[b] = 0;
    __syncthreads();
    int beg = c * chunk, end = min(beg + chunk, E);
    int nfull = (end - beg) >> 2;
    for (int g = tid; g < nfull; g += blockDim.x) {
        int4 c4 = *reinterpret_cast<const int4*>(col + beg + g * 4);
        atomicAdd(&h[c4.x >> 5], 1);
        atomicAdd(&h[c4.y >> 5], 1);
        atomicAdd(&h[c4.z >> 5], 1);
        atomicAdd(&h[c4.w >> 5], 1);
    }
    for (int e = beg + nfull * 4 + tid; e < end; e += blockDim.x)
        atomicAdd(&h[col[e] >> 5], 1);
    __syncthreads();
    for (int b = tid; b < NB; b += blockDim.x) {
        int v = h[b];
        lcur[b] = (v > 0) ? atomicAdd(&cursor[b], v) : 0;   // reserve block slice
    }
    __syncthreads();
    for (int g = tid; g < nfull; g += blockDim.x) {
        int e = beg + g * 4;
        int4 d4 = *reinterpret_cast<const int4*>(col + e);
        int4 s4 = *reinterpret_cast<const int4*>(row + e);
        int p0 = atomicAdd(&lcur[d4.x >> 5], 1);
        packed[p0] = (unsigned)s4.x | ((unsigned)(d4.x & 31) << 16);
        int p1 = atomicAdd(&lcur[d4.y >> 5], 1);
        packed[p1] = (unsigned)s4.y | ((unsigned)(d4.y & 31) << 16);
        int p2 = atomicAdd(&lcur[d4.z >> 5], 1);
        packed[p2] = (unsigned)s4.z | ((unsigned)(d4.z & 31) << 16);
        int p3 = atomicAdd(&lcur[d4.w >> 5], 1);
        packed[p3] = (unsigned)s4.w | ((unsigned)(d4.w & 31) << 16);
    }
    for (int e = beg + nfull * 4 + tid; e < end; e += blockDim.x) {
        int d = col[e];
        int p = atomicAdd(&lcur[d >> 5], 1);
        packed[p] = (unsigned)row[e] | ((unsigned)(d & 31) << 16);
    }
}

// ---- K2: per-bucket counting sort (no LDS buf; packed read twice from L2)
//      + 8-lane/row gather + mean ----
template <bool BF16>
__global__ __launch_bounds__(512)
void aggregate_bucket_kernel(const float* __restrict__ xf,
                             const ushort_t* __restrict__ xh,
                             const unsigned* __restrict__ packed,
                             const int* __restrict__ cursor,
                             float* __restrict__ out) {
    __shared__ unsigned short srcs[CAP];
    __shared__ int hist[NPB];
    __shared__ int segoff[NPB];
    __shared__ int lcur[NPB];
    __shared__ int cnt_tot[NPB];

    int b = blockIdx.x;
    int tid = threadIdx.x;                      // 0..511
    int lane = tid & 63;
    int wv = tid >> 6;                          // wave 0..7
    int g8 = lane >> 3;                         // row slot 0..7
    int o = lane & 7;                           // dim octet (dims o*8 .. o*8+7)
    int seg_beg = b * CAPB;
    int seg_end = cursor[b];                    // base + total after binning
    int node_base = b * NPB;
    int nnodes = min(NPB, N_NODES - node_base);

    float acc[4][8];
    #pragma unroll
    for (int r = 0; r < 4; ++r)
        #pragma unroll
        for (int k = 0; k < 8; ++k) acc[r][k] = 0.0f;
    if (tid < NPB) cnt_tot[tid] = 0;

    for (int cs = seg_beg; cs < seg_end; cs += CAP) {
        int m = min(CAP, seg_end - cs);
        __syncthreads();
        if (tid < NPB) hist[tid] = 0;
        __syncthreads();
        {   // pass 1: histogram, uint4-vectorized (cs is 1024-aligned)
            int nf = m >> 2;
            const uint4* p4 = reinterpret_cast<const uint4*>(packed + cs);
            for (int i = tid; i < nf; i += 512) {
                uint4 v = p4[i];
                atomicAdd(&hist[v.x >> 16], 1);
                atomicAdd(&hist[v.y >> 16], 1);
                atomicAdd(&hist[v.z >> 16], 1);
                atomicAdd(&hist[v.w >> 16], 1);
            }
            for (int i = nf * 4 + tid; i < m; i += 512)
                atomicAdd(&hist[packed[cs + i] >> 16], 1);
        }
        __syncthreads();
        if (tid < NPB) {                        // lanes 0..31 of wave 0: scan 32 bins
            int v = hist[tid];
            int incl = v;
            #pragma unroll
            for (int ofs = 1; ofs < 32; ofs <<= 1) {
                int t = __shfl_up(incl, ofs);
                if (lane >= ofs) incl += t;
            }
            segoff[tid] = incl - v;
            lcur[tid] = incl - v;
            cnt_tot[tid] += v;
        }
        __syncthreads();
        for (int i = tid; i < m; i += 512) {    // pass 2: scatter (packed L2-hit)
            unsigned v = packed[cs + i];
            int p = atomicAdd(&lcur[v >> 16], 1);
            srcs[p] = (unsigned short)(v & 0xFFFF);
        }
        __syncthreads();
        #pragma unroll
        for (int r = 0; r < 4; ++r) {
            int ln = wv * 4 + r;
            int st = segoff[ln];
            int len = hist[ln];
            int j = 0;
            for (; j + 16 <= len; j += 16) {    // 16 rows in flight per wave
                int s0 = srcs[st + j + g8];
                int s1 = srcs[st + j + 8 + g8];
                if (BF16) {
                    uint4 a0 = *reinterpret_cast<const uint4*>(xh + (size_t)s0 * DIM + o * 8);
                    uint4 a1 = *reinterpret_cast<const uint4*>(xh + (size_t)s1 * DIM + o * 8);
                    acc_pair(acc[r][0], acc[r][1], a0.x);
                    acc_pair(acc[r][2], acc[r][3], a0.y);
                    acc_pair(acc[r][4], acc[r][5], a0.z);
                    acc_pair(acc[r][6], acc[r][7], a0.w);
                    acc_pair(acc[r][0], acc[r][1], a1.x);
                    acc_pair(acc[r][2], acc[r][3], a1.y);
                    acc_pair(acc[r][4], acc[r][5], a1.z);
                    acc_pair(acc[r][6], acc[r][7], a1.w);
                } else {
                    float4 u0 = *reinterpret_cast<const float4*>(xf + (size_t)s0 * DIM + o * 8);
                    float4 u1 = *reinterpret_cast<const float4*>(xf + (size_t)s0 * DIM + o * 8 + 4);
                    float4 u2 = *reinterpret_cast<const float4*>(xf + (size_t)s1 * DIM + o * 8);
                    float4 u3 = *reinterpret_cast<const float4*>(xf + (size_t)s1 * DIM + o * 8 + 4);
                    acc[r][0] += u0.x + u2.x; acc[r][1] += u0.y + u2.y;
                    acc[r][2] += u0.z + u2.z; acc[r][3] += u0.w + u2.w;
                    acc[r][4] += u1.x + u3.x; acc[r][5] += u1.y + u3.y;
                    acc[r][6] += u1.z + u3.z; acc[r][7] += u1.w + u3.w;
                }
            }
            for (; j < len; j += 8) {
                if (j + g8 < len) {
                    int s = srcs[st + j + g8];
                    if (BF16) {
                        uint4 a0 = *reinterpret_cast<const uint4*>(xh + (size_t)s * DIM + o * 8);
                        acc_pair(acc[r][0], acc[r][1], a0.x);
                        acc_pair(acc[r][2], acc[r][3], a0.y);
                        acc_pair(acc[r][4], acc[r][5], a0.z);
                        acc_pair(acc[r][6], acc[r][7], a0.w);
                    } else {
                        float4 u0 = *reinterpret_cast<const float4*>(xf + (size_t)s * DIM + o * 8);
                        float4 u1 = *reinterpret_cast<const float4*>(xf + (size_t)s * DIM + o * 8 + 4);
                        acc[r][0] += u0.x; acc[r][1] += u0.y;
                        acc[r][2] += u0.z; acc[r][3] += u0.w;
                        acc[r][4] += u1.x; acc[r][5] += u1.y;
                        acc[r][6] += u1.z; acc[r][7] += u1.w;
                    }
                }
            }
        }
    }
    __syncthreads();
    // reduce across row slots (xor 8,16,32) + mean + store
    #pragma unroll
    for (int r = 0; r < 4; ++r) {
        int ln = wv * 4 + r;
        #pragma unroll
        for (int k = 0; k < 8; ++k) {
            acc[r][k] += __shfl_xor(acc[r][k], 8);
            acc[r][k] += __shfl_xor(acc[r][k], 16);
            acc[r][k] += __shfl_xor(acc[r][k], 32);
        }
        if (g8 == 0 && ln < nnodes) {
            int c = cnt_tot[ln];
            float inv = (c > 0) ? 1.0f / (float)c : 0.0f;
            float4 lo = make_float4(acc[r][0] * inv, acc[r][1] * inv,
                                    acc[r][2] * inv, acc[r][3] * inv);
            float4 hi = make_float4(acc[r][4] * inv, acc[r][5] * inv,
                                    acc[r][6] * inv, acc[r][7] * inv);
            float* op = out + (size_t)(node_base + ln) * DIM + o * 8;
            *reinterpret_cast<float4*>(op) = lo;
            *reinterpret_cast<float4*>(op + 4) = hi;
        }
    }
}

extern "C" void kernel_launch(void* const* d_in, const int* in_sizes, int n_in,
                              void* d_out, int out_size, void* d_ws, size_t ws_size,
                              hipStream_t stream) {
    const float* x = (const float*)d_in[0];
    const int* edge_index = (const int*)d_in[1];  // [2, E] flat: row then col
    int E = in_sizes[1] / 2;
    const int* row = edge_index;
    const int* col = edge_index + E;
    float* out = (float*)d_out;

    int chunk = (((E + NCHUNK - 1) / NCHUNK) + 3) & ~3;   // multiple of 4
    int n4 = N_NODES * DIM / 4;

    // ws: cursor 1568 | packed NB*CAPB | xh N*DIM bf16
    int* cursor      = (int*)d_ws;
    unsigned* packed = (unsigned*)(cursor + 1568);
    ushort_t* xh     = (ushort_t*)(packed + (size_t)NB * CAPB);
    size_t need_bf16 = (size_t)((char*)(xh + (size_t)N_NODES * DIM) - (char*)d_ws);
    bool use_bf16 = (ws_size >= need_bf16);

    init_cursor_kernel<<<7, 256, 0, stream>>>(cursor);
    binning_kernel<<<NCHUNK, 1024, 0, stream>>>(x, xh, row, col, cursor, packed,
                                                E, chunk, use_bf16 ? n4 : 0);
    if (use_bf16)
        aggregate_bucket_kernel<true><<<NB, 512, 0, stream>>>(x, xh, packed, cursor, out);
    else
        aggregate_bucket_kernel<false><<<NB, 512, 0, stream>>>(x, xh, packed, cursor, out);
}